// Round 6
// baseline (403.303 us; speedup 1.0000x reference)
//
#include <hip/hip_runtime.h>

// SSIM loss, round 6 (= round 5 with types fixed): f16 dot2 pipeline.
// imgs: (32, 3, 512, 512) fp32. Output: scalar 1 - mean(ssim_map).
//
// Per block: 32x32 output tile.
//  staging: 42 rows x 48 cols (gx in [tx-8, tx+39], 16B-aligned quads).
//    5 quantity arrays {x1, x2, x1^2, x2^2, x1*x2} stored as f16 PAIRS PACKED
//    ALONG X (cvt_pkrtz + v_pk_mul_f16). Zero-fill = conv zero padding.
//  phase 2 (horizontal blur): per element, per quantity: 6 dwords read +
//    6 v_dot2_f32_f16 (f32 accumulate). Weight-pairs selected once per thread
//    by column parity. Results held in REGISTERS (res[6][5]).
//  barrier; H region (f16 packed along y, stride 23 dwords/col) OVERLAYS the
//    A region -> peak LDS ~21.8 KB -> 7 blocks/CU target.
//  phase 3 (vertical blur): per quantity 7 dword reads + 6 dot2 per output
//    (row parity compile-time). SSIM formula (v_rcp_f32), wave reduce,
//    spread atomics.

#define HH 512
#define WW 512
#define TILE 32
#define IN_ROWS 42
#define SDW 26                    // A: dword stride per row (24 used + 2 pad)
#define AQ_BYTES (IN_ROWS * SDW * 4)     // 4368
#define HDW 23                    // H: dword stride per col (21 used + 2 pad, odd)
#define HQ_BYTES (TILE * HDW * 4)        // 2944
#define UNION_BYTES (5 * AQ_BYTES)       // 21840 (> 5*HQ_BYTES = 14720)
#define NPLANES 96
#define NPIX 25165824.0f
#define NACC 256

#define G0 1.0283800e-03f
#define G1 7.5987600e-03f
#define G2 3.6000770e-02f
#define G3 1.0936072e-01f
#define G4 2.1300560e-01f
#define G5 2.6601170e-01f
#define G6 2.1300560e-01f
#define G7 1.0936072e-01f
#define G8 3.6000770e-02f
#define G9 7.5987600e-03f
#define G10 1.0283800e-03f

typedef float v4f __attribute__((ext_vector_type(4)));
typedef __fp16 h2 __attribute__((ext_vector_type(2)));   // matches cvt_pkrtz / fdot2

#define H2C(a, b) ((h2){(__fp16)(a), (__fp16)(b)})

static __device__ __forceinline__ unsigned bc(h2 v) {
  return __builtin_bit_cast(unsigned, v);
}
static __device__ __forceinline__ h2 bh(unsigned u) {
  return __builtin_bit_cast(h2, u);
}
static __device__ __forceinline__ float dot2(unsigned d, h2 w, float s) {
  return __builtin_amdgcn_fdot2(bh(d), w, s, false);
}

__global__ __launch_bounds__(256, 7) void ssim_fused_kernel(
    const float* __restrict__ img1, const float* __restrict__ img2,
    float* __restrict__ acc) {
  __shared__ __align__(16) char ub[UNION_BYTES];
  __shared__ float wsum[4];

  const int tid = threadIdx.x;
  const int tx = blockIdx.x * TILE;
  const int ty = blockIdx.y * TILE;
  const size_t base = (size_t)blockIdx.z * (HH * WW);

  // ---- staging: 42 rows x 12 quads = 504 ----
#pragma unroll
  for (int it = 0; it < 2; ++it) {
    int idx = it * 256 + tid;
    if (idx < IN_ROWS * 12) {
      int r = idx / 12;
      int p = idx - r * 12;
      int gy = ty - 5 + r;
      int gx = tx - 8 + 4 * p;
      v4f A = {0.f, 0.f, 0.f, 0.f}, B = {0.f, 0.f, 0.f, 0.f};
      if ((unsigned)gy < (unsigned)HH && (unsigned)gx < (unsigned)WW) {
        size_t off = base + (size_t)gy * WW + gx;
        A = *(const v4f*)(img1 + off);
        B = *(const v4f*)(img2 + off);
      }
      h2 x1a = __builtin_amdgcn_cvt_pkrtz(A.x, A.y);
      h2 x1b = __builtin_amdgcn_cvt_pkrtz(A.z, A.w);
      h2 x2a = __builtin_amdgcn_cvt_pkrtz(B.x, B.y);
      h2 x2b = __builtin_amdgcn_cvt_pkrtz(B.z, B.w);
      h2 s1a = x1a * x1a, s1b = x1b * x1b;      // v_pk_mul_f16
      h2 s2a = x2a * x2a, s2b = x2b * x2b;
      h2 xya = x1a * x2a, xyb = x1b * x2b;
      char* wp = ub + (r * SDW + 2 * p) * 4;    // 8B-aligned
      *(uint2*)(wp + 0 * AQ_BYTES) = make_uint2(bc(x1a), bc(x1b));
      *(uint2*)(wp + 1 * AQ_BYTES) = make_uint2(bc(x2a), bc(x2b));
      *(uint2*)(wp + 2 * AQ_BYTES) = make_uint2(bc(s1a), bc(s1b));
      *(uint2*)(wp + 3 * AQ_BYTES) = make_uint2(bc(s2a), bc(s2b));
      *(uint2*)(wp + 4 * AQ_BYTES) = make_uint2(bc(xya), bc(xyb));
    }
  }
  __syncthreads();

  // ---- phase 2: horizontal blur via dot2, results -> registers ----
  const int c = tid & 31;
  const int w = tid >> 5;
  const int k0 = (c + 3) >> 1;       // first dword of the 6-dword tap window
  const bool codd = (c & 1) != 0;
  // c even: first tap lands in the HIGH half of dword k0 -> shifted set.
  const h2 wp0 = codd ? H2C(G0, G1) : H2C(0.f, G0);
  const h2 wp1 = codd ? H2C(G2, G3) : H2C(G1, G2);
  const h2 wp2 = codd ? H2C(G4, G5) : H2C(G3, G4);
  const h2 wp3 = codd ? H2C(G6, G7) : H2C(G5, G6);
  const h2 wp4 = codd ? H2C(G8, G9) : H2C(G7, G8);
  const h2 wp5 = codd ? H2C(G10, 0.f) : H2C(G9, G10);

  float res[6][5];
#pragma unroll
  for (int it = 0; it < 6; ++it) {
    int r = it * 8 + w;
    if (r < IN_ROWS) {
      const char* ap = ub + (r * SDW + k0) * 4;
#pragma unroll
      for (int q = 0; q < 5; ++q) {
        const unsigned* dp = (const unsigned*)(ap + q * AQ_BYTES);
        float s = 0.f;
        s = dot2(dp[0], wp0, s);
        s = dot2(dp[1], wp1, s);
        s = dot2(dp[2], wp2, s);
        s = dot2(dp[3], wp3, s);
        s = dot2(dp[4], wp4, s);
        s = dot2(dp[5], wp5, s);
        res[it][q] = s;
      }
    }
  }
  __syncthreads();   // all A reads done; overlay H on the union

  // ---- write H: f16 packed along y. half-index: q*(HQ/2) + c*46 + r ----
  __fp16* hb = (__fp16*)ub;
#pragma unroll
  for (int it = 0; it < 6; ++it) {
    int r = it * 8 + w;
    if (r < IN_ROWS) {
#pragma unroll
      for (int q = 0; q < 5; ++q)
        hb[q * (HQ_BYTES / 2) + c * (HDW * 2) + r] = (__fp16)res[it][q];
    }
  }
  __syncthreads();

  // ---- phase 3: vertical blur via dot2 + SSIM ----
  // thread -> (col c, rows 4w..4w+3); dwords c*HDW + 2w .. +6.
  const char* hp = ub + c * (HDW * 4) + w * 8;
  float accq[5][4];
#pragma unroll
  for (int q = 0; q < 5; ++q) {
    const unsigned* dp = (const unsigned*)(hp + q * HQ_BYTES);
    unsigned d0 = dp[0], d1 = dp[1], d2 = dp[2], d3 = dp[3];
    unsigned d4 = dp[4], d5 = dp[5], d6 = dp[6];
    float s;
    // o=0: rows 4w..4w+10, even start, d0..d5
    s = 0.f;
    s = dot2(d0, H2C(G0, G1), s);  s = dot2(d1, H2C(G2, G3), s);
    s = dot2(d2, H2C(G4, G5), s);  s = dot2(d3, H2C(G6, G7), s);
    s = dot2(d4, H2C(G8, G9), s);  s = dot2(d5, H2C(G10, 0.f), s);
    accq[q][0] = s;
    // o=1: odd start, d0..d5
    s = 0.f;
    s = dot2(d0, H2C(0.f, G0), s); s = dot2(d1, H2C(G1, G2), s);
    s = dot2(d2, H2C(G3, G4), s);  s = dot2(d3, H2C(G5, G6), s);
    s = dot2(d4, H2C(G7, G8), s);  s = dot2(d5, H2C(G9, G10), s);
    accq[q][1] = s;
    // o=2: even start, d1..d6
    s = 0.f;
    s = dot2(d1, H2C(G0, G1), s);  s = dot2(d2, H2C(G2, G3), s);
    s = dot2(d3, H2C(G4, G5), s);  s = dot2(d4, H2C(G6, G7), s);
    s = dot2(d5, H2C(G8, G9), s);  s = dot2(d6, H2C(G10, 0.f), s);
    accq[q][2] = s;
    // o=3: odd start, d1..d6
    s = 0.f;
    s = dot2(d1, H2C(0.f, G0), s); s = dot2(d2, H2C(G1, G2), s);
    s = dot2(d3, H2C(G3, G4), s);  s = dot2(d4, H2C(G5, G6), s);
    s = dot2(d5, H2C(G7, G8), s);  s = dot2(d6, H2C(G9, G10), s);
    accq[q][3] = s;
  }

  const float C1 = 1e-4f;
  const float C2 = 9e-4f;
  float lsum = 0.f;
#pragma unroll
  for (int o = 0; o < 4; ++o) {
    float mu1 = accq[0][o], mu2 = accq[1][o];
    float b11 = accq[2][o], b22 = accq[3][o], b12 = accq[4][o];
    float mu1sq = mu1 * mu1;
    float mu2sq = mu2 * mu2;
    float mu12 = mu1 * mu2;
    float sig11 = b11 - mu1sq;
    float sig22 = b22 - mu2sq;
    float sig12 = b12 - mu12;
    float num = (2.f * mu12 + C1) * (2.f * sig12 + C2);
    float den = (mu1sq + mu2sq + C1) * (sig11 + sig22 + C2);
    lsum += num * __builtin_amdgcn_rcpf(den);
  }

  // wave reduction + one atomic per block into spread slots
#pragma unroll
  for (int off = 32; off > 0; off >>= 1)
    lsum += __shfl_down(lsum, off, 64);
  const int lane = tid & 63;
  const int wid = tid >> 6;
  if (lane == 0) wsum[wid] = lsum;
  __syncthreads();
  if (tid == 0) {
    float b = wsum[0] + wsum[1] + wsum[2] + wsum[3];
    int slot = (blockIdx.x + blockIdx.y * 16 + blockIdx.z) & (NACC - 1);
    atomicAdd(acc + slot, b);
  }
}

__global__ void ssim_finalize_kernel(const float* __restrict__ acc,
                                     float* __restrict__ out) {
  __shared__ float wsum[4];
  const int tid = threadIdx.x;
  float s = acc[tid];
#pragma unroll
  for (int off = 32; off > 0; off >>= 1)
    s += __shfl_down(s, off, 64);
  if ((tid & 63) == 0) wsum[tid >> 6] = s;
  __syncthreads();
  if (tid == 0)
    out[0] = 1.0f - (wsum[0] + wsum[1] + wsum[2] + wsum[3]) * (1.0f / NPIX);
}

extern "C" void kernel_launch(void* const* d_in, const int* in_sizes, int n_in,
                              void* d_out, int out_size, void* d_ws, size_t ws_size,
                              hipStream_t stream) {
  const float* img1 = (const float*)d_in[0];
  const float* img2 = (const float*)d_in[1];
  float* out = (float*)d_out;
  float* acc = (float*)d_ws;

  (void)hipMemsetAsync(acc, 0, NACC * sizeof(float), stream);

  dim3 grid(WW / TILE, HH / TILE, NPLANES);   // 16 x 16 x 96 = 24576
  ssim_fused_kernel<<<grid, 256, 0, stream>>>(img1, img2, acc);
  ssim_finalize_kernel<<<1, NACC, 0, stream>>>(acc, out);
}

// Round 7
// 282.171 us; speedup vs baseline: 1.4293x; 1.4293x over previous
//
#include <hip/hip_runtime.h>

// SSIM loss, round 7: round-4 structure + phase-2 x-register-sliding.
// imgs: (32, 3, 512, 512) fp32. Output: scalar 1 - mean(ssim_map).
//
// Per block: 32x32 output tile, fp32 throughout (round 6's f16 attempt
// spilled to scratch: WRITE_SIZE 467 MB).
//  phase 1: stage 42x48 (x1,x2)-interleaved v2f tile (float4 global loads).
//  phase 2: 672 tasks = 42 rows x 16 col-PAIRS. Each task: 7 ds_read_b128
//           (14 v2f, 16B-aligned since c+2 and stride 50 are even), computes
//           both columns' {h01,h23,h4} by sliding the 11-tap window ->
//           REGISTERS (30 f32 held, same footprint round 4 proved at 44 VGPR).
//           Cuts p2 LDS read bytes ~40% vs per-column b64 taps.
//  barrier; H arrays (stride 34 v2f -> b128-aligned writes) OVERLAY the
//           staging region; writes are 2xb128 + 1xb64 per task.
//  phase 3: vertical blur, 4 consecutive rows/thread, sliding 14-tap window,
//           SSIM with v_rcp_f32, wave reduce, spread atomics.

#define HH 512
#define WW 512
#define TILE 32
#define IN_ROWS 42
#define S_STRIDE 50         // v2f stride of s12 (even -> b128 alignment holds)
#define H_STRIDE 34         // v2f/f32 stride of h arrays (even -> b128 writes)
#define NPLANES 96
#define NPIX 25165824.0f
#define NACC 256
#define NTASK 672           // 42 rows * 16 col-pairs

// union layout (bytes)
#define H01_OFF 0                    // v2f [42][34] = 11424
#define H23_OFF 11424                // v2f [42][34] = 11424
#define H4_OFF  22848                // f32 [42][34] = 5712
#define UNION_BYTES 28560            // >= s12: v2f[42][50] = 16800

typedef float v2f __attribute__((ext_vector_type(2)));
typedef float v4f __attribute__((ext_vector_type(4)));

__global__ __launch_bounds__(256, 5) void ssim_fused_kernel(
    const float* __restrict__ img1, const float* __restrict__ img2,
    float* __restrict__ acc) {
  __shared__ __align__(16) char ub[UNION_BYTES];
  __shared__ float wsum[4];

  v2f (*s12)[S_STRIDE] = (v2f (*)[S_STRIDE])ub;
  v2f (*h01)[H_STRIDE] = (v2f (*)[H_STRIDE])(ub + H01_OFF);
  v2f (*h23)[H_STRIDE] = (v2f (*)[H_STRIDE])(ub + H23_OFF);
  float (*h4)[H_STRIDE] = (float (*)[H_STRIDE])(ub + H4_OFF);

  const int tid = threadIdx.x;
  const int tx = blockIdx.x * TILE;
  const int ty = blockIdx.y * TILE;
  const size_t base = (size_t)blockIdx.z * (HH * WW);

  const float g[11] = {
      1.0283800e-03f, 7.5987600e-03f, 3.6000770e-02f, 1.0936072e-01f,
      2.1300560e-01f, 2.6601170e-01f, 2.1300560e-01f, 1.0936072e-01f,
      3.6000770e-02f, 7.5987600e-03f, 1.0283800e-03f};

  // ---- phase 1: float4 staging, interleave (x1,x2) into s12 ----
  // pixel slot = gx - (tx-8); 42 rows x 12 quads; quads 16B-aligned in global.
#pragma unroll
  for (int it = 0; it < 2; ++it) {
    int idx = it * 256 + tid;
    if (idx < IN_ROWS * 12) {
      int r = idx / 12;
      int p = idx - r * 12;
      int gy = ty - 5 + r;
      int gx = tx - 8 + 4 * p;
      v4f A = {0.f, 0.f, 0.f, 0.f}, B = {0.f, 0.f, 0.f, 0.f};
      if ((unsigned)gy < (unsigned)HH && (unsigned)gx < (unsigned)WW) {
        size_t off = base + (size_t)gy * WW + gx;
        A = *(const v4f*)(img1 + off);
        B = *(const v4f*)(img2 + off);
      }
      *(v4f*)&s12[r][4 * p]     = (v4f){A.x, B.x, A.y, B.y};
      *(v4f*)&s12[r][4 * p + 2] = (v4f){A.z, B.z, A.w, B.w};
    }
  }
  __syncthreads();

  // ---- phase 2: horizontal blur, 2 output cols per task, b128 tap reads ----
  // task (r, cp): c = 2*cp; taps for col c are pixel slots c+3..c+13,
  // for col c+1 slots c+4..c+14. Read slots c+2..c+15 as 7 b128.
  v2f hold01[3][2], hold23[3][2], hold4[3];
#pragma unroll
  for (int t = 0; t < 3; ++t) {
    int idx = t * 256 + tid;
    if (idx < NTASK) {
      int r = idx >> 4;
      int c = (idx & 15) * 2;
      const v4f* qp = (const v4f*)&s12[r][c + 2];   // 16B-aligned
      v4f q0 = qp[0], q1 = qp[1], q2 = qp[2], q3 = qp[3];
      v4f q4 = qp[4], q5 = qp[5], q6 = qp[6];
      v2f P[14];
      P[0]  = (v2f){q0.x, q0.y};  P[1]  = (v2f){q0.z, q0.w};
      P[2]  = (v2f){q1.x, q1.y};  P[3]  = (v2f){q1.z, q1.w};
      P[4]  = (v2f){q2.x, q2.y};  P[5]  = (v2f){q2.z, q2.w};
      P[6]  = (v2f){q3.x, q3.y};  P[7]  = (v2f){q3.z, q3.w};
      P[8]  = (v2f){q4.x, q4.y};  P[9]  = (v2f){q4.z, q4.w};
      P[10] = (v2f){q5.x, q5.y};  P[11] = (v2f){q5.z, q5.w};
      P[12] = (v2f){q6.x, q6.y};  P[13] = (v2f){q6.z, q6.w};

      v2f a01_0 = (v2f){0.f, 0.f}, a23_0 = (v2f){0.f, 0.f};
      v2f a01_1 = (v2f){0.f, 0.f}, a23_1 = (v2f){0.f, 0.f};
      float a4_0 = 0.f, a4_1 = 0.f;
#pragma unroll
      for (int dx = 0; dx < 11; ++dx) {
        float w = g[dx];
        v2f v0 = P[1 + dx];
        v2f v1 = P[2 + dx];
        a01_0 += w * v0;
        a01_1 += w * v1;
        a23_0 += w * (v0 * v0);
        a23_1 += w * (v1 * v1);
        a4_0 = __builtin_fmaf(w, v0.x * v0.y, a4_0);
        a4_1 = __builtin_fmaf(w, v1.x * v1.y, a4_1);
      }
      hold01[t][0] = a01_0;  hold01[t][1] = a01_1;
      hold23[t][0] = a23_0;  hold23[t][1] = a23_1;
      hold4[t] = (v2f){a4_0, a4_1};
    }
  }
  __syncthreads();   // all s12 reads done; overlay H on the union

#pragma unroll
  for (int t = 0; t < 3; ++t) {
    int idx = t * 256 + tid;
    if (idx < NTASK) {
      int r = idx >> 4;
      int c = (idx & 15) * 2;
      *(v4f*)&h01[r][c] = (v4f){hold01[t][0].x, hold01[t][0].y,
                                hold01[t][1].x, hold01[t][1].y};
      *(v4f*)&h23[r][c] = (v4f){hold23[t][0].x, hold23[t][0].y,
                                hold23[t][1].x, hold23[t][1].y};
      *(v2f*)&h4[r][c] = hold4[t];
    }
  }
  __syncthreads();

  // ---- phase 3: vertical blur, 4 consecutive rows/thread, sliding window ----
  const float C1 = 1e-4f;
  const float C2 = 9e-4f;
  const int c = tid & 31;
  const int r0 = (tid >> 5) * 4;

  v2f m[4], vv[4];
  float b12[4];
#pragma unroll
  for (int o = 0; o < 4; ++o) {
    m[o] = (v2f){0.f, 0.f};
    vv[o] = (v2f){0.f, 0.f};
    b12[o] = 0.f;
  }

#pragma unroll
  for (int dy = 0; dy < 14; ++dy) {
    v2f a = h01[r0 + dy][c];
    v2f b = h23[r0 + dy][c];
    float d = h4[r0 + dy][c];
#pragma unroll
    for (int o = 0; o < 4; ++o) {
      const int k = dy - o;
      if (k >= 0 && k < 11) {
        float w = g[k];
        m[o] += w * a;
        vv[o] += w * b;
        b12[o] = __builtin_fmaf(w, d, b12[o]);
      }
    }
  }

  float lsum = 0.f;
#pragma unroll
  for (int o = 0; o < 4; ++o) {
    float mu1 = m[o].x, mu2 = m[o].y;
    float mu1sq = mu1 * mu1;
    float mu2sq = mu2 * mu2;
    float mu12 = mu1 * mu2;
    float sig11 = vv[o].x - mu1sq;
    float sig22 = vv[o].y - mu2sq;
    float sig12 = b12[o] - mu12;
    float num = (2.f * mu12 + C1) * (2.f * sig12 + C2);
    float den = (mu1sq + mu2sq + C1) * (sig11 + sig22 + C2);
    lsum += num * __builtin_amdgcn_rcpf(den);
  }

  // wave reduction + one atomic per block into spread slots
#pragma unroll
  for (int off = 32; off > 0; off >>= 1)
    lsum += __shfl_down(lsum, off, 64);
  const int lane = tid & 63;
  const int wid = tid >> 6;
  if (lane == 0) wsum[wid] = lsum;
  __syncthreads();
  if (tid == 0) {
    float b = wsum[0] + wsum[1] + wsum[2] + wsum[3];
    int slot = (blockIdx.x + blockIdx.y * 16 + blockIdx.z) & (NACC - 1);
    atomicAdd(acc + slot, b);
  }
}

__global__ void ssim_finalize_kernel(const float* __restrict__ acc,
                                     float* __restrict__ out) {
  __shared__ float wsum[4];
  const int tid = threadIdx.x;
  float s = acc[tid];
#pragma unroll
  for (int off = 32; off > 0; off >>= 1)
    s += __shfl_down(s, off, 64);
  if ((tid & 63) == 0) wsum[tid >> 6] = s;
  __syncthreads();
  if (tid == 0)
    out[0] = 1.0f - (wsum[0] + wsum[1] + wsum[2] + wsum[3]) * (1.0f / NPIX);
}

extern "C" void kernel_launch(void* const* d_in, const int* in_sizes, int n_in,
                              void* d_out, int out_size, void* d_ws, size_t ws_size,
                              hipStream_t stream) {
  const float* img1 = (const float*)d_in[0];
  const float* img2 = (const float*)d_in[1];
  float* out = (float*)d_out;
  float* acc = (float*)d_ws;

  (void)hipMemsetAsync(acc, 0, NACC * sizeof(float), stream);

  dim3 grid(WW / TILE, HH / TILE, NPLANES);   // 16 x 16 x 96 = 24576
  ssim_fused_kernel<<<grid, 256, 0, stream>>>(img1, img2, acc);
  ssim_finalize_kernel<<<1, NACC, 0, stream>>>(acc, out);
}